// Round 7
// baseline (322.158 us; speedup 1.0000x reference)
//
#include <hip/hip_runtime.h>

// MNIST_RNN R7: amortize the LDS weight broadcasts (60% of the LDS pipe in
// the R6 model) over 2 samples per lane. 8 gate-parallel waves x 128
// samples/block (lane owns samples lane and lane+64); grid 256 = 1 block/CU.
// Each uniform weight b128 now feeds 8 FMAs (2 samples) -> per-sample weight
// LDS traffic halves: ~5.8k LDS cyc/t/CU vs R6's ~10k for the same 128
// samples/CU. VALU ~3.7k/t/SIMD -> balanced pipes. launch_bounds(512,1)
// (2nd arg = blocks/CU semantics, learned in R5) -> 256 VGPR cap, no spill
// at ~175 live. Everything else per R6: weights as uniform ds_read_b128
// from LDS, g-exchange [row][sample], redundant P2, x via global_load_lds.

#define HDIM 10
#define DDIM 28
#define TSTEPS 28
#define SPB 128          // samples per block (2 per lane)

typedef const __attribute__((address_space(1))) unsigned int gu32;
typedef __attribute__((address_space(3))) unsigned int lu32;

__device__ __forceinline__ void gld_lds16(const float* g, float4* l) {
    __builtin_amdgcn_global_load_lds((gu32*)g, (lu32*)l, 16, 0, 0);
}

__device__ __forceinline__ float fast_sigmoid(float v) {
    return __builtin_amdgcn_rcpf(1.0f + __expf(-v));
}
__device__ __forceinline__ float fast_tanh(float v) {
    return 2.0f * __builtin_amdgcn_rcpf(1.0f + __expf(-2.0f * v)) - 1.0f;
}

__global__ __launch_bounds__(512, 1) void lstm2_cls_kernel(
    const float* __restrict__ x,
    const float* __restrict__ w_ih0, const float* __restrict__ w_hh0,
    const float* __restrict__ b_ih0, const float* __restrict__ b_hh0,
    const float* __restrict__ w_ih1, const float* __restrict__ w_hh1,
    const float* __restrict__ b_ih1, const float* __restrict__ b_hh1,
    const float* __restrict__ w_cls, const float* __restrict__ b_cls,
    float* __restrict__ out)
{
    __shared__ float4 sx[2][7 * SPB];  // x tiles [buf][v*SPB + s]    28672 B
    __shared__ float g0[40 * SPB];     // activated L0 gates          20480 B
    __shared__ float g1[40 * SPB];     //                             20480 B
    __shared__ float wW0[40 * 40];     // [row][28 x | 10 h | 2 pad]   6400 B
    __shared__ float wW1[40 * 20];     // [row][10 ih | 10 hh]         3200 B
    __shared__ float sb0[40], sb1[40];

    const int tid  = threadIdx.x;
    const int lane = tid & 63;
    const int wid  = __builtin_amdgcn_readfirstlane(tid >> 6);
    const int b0   = blockIdx.x * SPB;
    const int sA   = b0 + lane;          // sample A
    const int sB   = sA + 64;            // sample B

    const int q     = wid >> 1;               // gate 0=i 1=f 2=g 3=o
    const int rbase = q * 10 + (wid & 1) * 5; // this wave's 5 rows
    const bool is_g = (q == 2);

    const float* xsA = x + (size_t)sA * (TSTEPS * DDIM);
    const float* xsB = x + (size_t)sB * (TSTEPS * DDIM);

    // DMA t=0 x tile: wave w deposits float4-column w for both sample halves
    if (wid < 7) {
        gld_lds16(xsA + 4 * wid, &sx[0][wid * SPB + lane]);
        gld_lds16(xsB + 4 * wid, &sx[0][wid * SPB + 64 + lane]);
    }

    // stage packed weights into LDS (once)
    for (int i = tid; i < 40 * 40; i += 512) {
        const int r = i / 40, c = i - r * 40;
        float v = 0.0f;
        if (c < DDIM)             v = w_ih0[r * DDIM + c];
        else if (c < DDIM + HDIM) v = w_hh0[r * HDIM + (c - DDIM)];
        wW0[i] = v;
    }
    for (int i = tid; i < 40 * 20; i += 512) {
        const int r = i / 20, c = i - r * 20;
        wW1[i] = (c < HDIM) ? w_ih1[r * HDIM + c] : w_hh1[r * HDIM + (c - HDIM)];
    }
    for (int i = tid; i < 40; i += 512) {
        sb0[i] = b_ih0[i] + b_hh0[i];
        sb1[i] = b_ih1[i] + b_hh1[i];
    }

    float h0A[HDIM], c0A[HDIM], h1A[HDIM], c1A[HDIM];
    float h0B[HDIM], c0B[HDIM], h1B[HDIM], c1B[HDIM];
    #pragma unroll
    for (int u = 0; u < HDIM; ++u) {
        h0A[u] = c0A[u] = h1A[u] = c1A[u] = 0.0f;
        h0B[u] = c0B[u] = h1B[u] = c1B[u] = 0.0f;
    }

    __syncthreads();   // weights + t=0 DMA visible

    float bias0[5], bias1[5];
    #pragma unroll
    for (int k = 0; k < 5; ++k) {
        bias0[k] = sb0[rbase + k];
        bias1[k] = sb1[rbase + k];
    }

    #pragma unroll 1
    for (int t = 0; t < TSTEPS; ++t) {
        const int cur = t & 1;

        if (t + 1 < TSTEPS && wid < 7) {
            gld_lds16(xsA + (t + 1) * DDIM + 4 * wid, &sx[cur ^ 1][wid * SPB + lane]);
            gld_lds16(xsB + (t + 1) * DDIM + 4 * wid, &sx[cur ^ 1][wid * SPB + 64 + lane]);
        }

        // x rows for both samples (14x ds_read_b128, lane-distinct)
        float4 xA[7], xB[7];
        #pragma unroll
        for (int v = 0; v < 7; ++v) {
            xA[v] = sx[cur][v * SPB + lane];
            xB[v] = sx[cur][v * SPB + 64 + lane];
        }

        // ---- P1/L0: 5 rows; each weight b128 feeds both samples ----
        #pragma unroll
        for (int k = 0; k < 5; ++k) {
            const float4* wp = (const float4*)&wW0[(rbase + k) * 40];
            float aA = bias0[k], aB = bias0[k];
            #pragma unroll
            for (int v = 0; v < 7; ++v) {
                const float4 w = wp[v];
                aA += xA[v].x*w.x + xA[v].y*w.y + xA[v].z*w.z + xA[v].w*w.w;
                aB += xB[v].x*w.x + xB[v].y*w.y + xB[v].z*w.z + xB[v].w*w.w;
            }
            { const float4 w = wp[7];
              aA += h0A[0]*w.x + h0A[1]*w.y + h0A[2]*w.z + h0A[3]*w.w;
              aB += h0B[0]*w.x + h0B[1]*w.y + h0B[2]*w.z + h0B[3]*w.w; }
            { const float4 w = wp[8];
              aA += h0A[4]*w.x + h0A[5]*w.y + h0A[6]*w.z + h0A[7]*w.w;
              aB += h0B[4]*w.x + h0B[5]*w.y + h0B[6]*w.z + h0B[7]*w.w; }
            { const float4 w = wp[9];
              aA += h0A[8]*w.x + h0A[9]*w.y;
              aB += h0B[8]*w.x + h0B[9]*w.y; }
            const int gi = (rbase + k) * SPB + lane;
            g0[gi]      = is_g ? fast_tanh(aA) : fast_sigmoid(aA);
            g0[gi + 64] = is_g ? fast_tanh(aB) : fast_sigmoid(aB);
        }
        __syncthreads();   // BAR-A

        // ---- P2/L0: redundant c0/h0 update, both samples ----
        #pragma unroll
        for (int u = 0; u < HDIM; ++u) {
            const int gi = u * SPB + lane;
            { const float iv = g0[gi], fv = g0[10*SPB + gi],
                          gv = g0[20*SPB + gi], ov = g0[30*SPB + gi];
              const float c = fv * c0A[u] + iv * gv;
              c0A[u] = c; h0A[u] = ov * fast_tanh(c); }
            { const float iv = g0[gi+64], fv = g0[10*SPB + gi+64],
                          gv = g0[20*SPB + gi+64], ov = g0[30*SPB + gi+64];
              const float c = fv * c0B[u] + iv * gv;
              c0B[u] = c; h0B[u] = ov * fast_tanh(c); }
        }

        // ---- P1/L1: 5 rows; weight b128 feeds both samples ----
        #pragma unroll
        for (int k = 0; k < 5; ++k) {
            const float4* wp = (const float4*)&wW1[(rbase + k) * 20];
            float aA = bias1[k], aB = bias1[k];
            { const float4 w = wp[0];
              aA += h0A[0]*w.x + h0A[1]*w.y + h0A[2]*w.z + h0A[3]*w.w;
              aB += h0B[0]*w.x + h0B[1]*w.y + h0B[2]*w.z + h0B[3]*w.w; }
            { const float4 w = wp[1];
              aA += h0A[4]*w.x + h0A[5]*w.y + h0A[6]*w.z + h0A[7]*w.w;
              aB += h0B[4]*w.x + h0B[5]*w.y + h0B[6]*w.z + h0B[7]*w.w; }
            { const float4 w = wp[2];
              aA += h0A[8]*w.x + h0A[9]*w.y + h1A[0]*w.z + h1A[1]*w.w;
              aB += h0B[8]*w.x + h0B[9]*w.y + h1B[0]*w.z + h1B[1]*w.w; }
            { const float4 w = wp[3];
              aA += h1A[2]*w.x + h1A[3]*w.y + h1A[4]*w.z + h1A[5]*w.w;
              aB += h1B[2]*w.x + h1B[3]*w.y + h1B[4]*w.z + h1B[5]*w.w; }
            { const float4 w = wp[4];
              aA += h1A[6]*w.x + h1A[7]*w.y + h1A[8]*w.z + h1A[9]*w.w;
              aB += h1B[6]*w.x + h1B[7]*w.y + h1B[8]*w.z + h1B[9]*w.w; }
            const int gi = (rbase + k) * SPB + lane;
            g1[gi]      = is_g ? fast_tanh(aA) : fast_sigmoid(aA);
            g1[gi + 64] = is_g ? fast_tanh(aB) : fast_sigmoid(aB);
        }
        __syncthreads();   // BAR-B (also drains DMA prefetch)

        // ---- P2/L1: redundant c1/h1 update, both samples ----
        #pragma unroll
        for (int u = 0; u < HDIM; ++u) {
            const int gi = u * SPB + lane;
            { const float iv = g1[gi], fv = g1[10*SPB + gi],
                          gv = g1[20*SPB + gi], ov = g1[30*SPB + gi];
              const float c = fv * c1A[u] + iv * gv;
              c1A[u] = c; h1A[u] = ov * fast_tanh(c); }
            { const float iv = g1[gi+64], fv = g1[10*SPB + gi+64],
                          gv = g1[20*SPB + gi+64], ov = g1[30*SPB + gi+64];
              const float c = fv * c1B[u] + iv * gv;
              c1B[u] = c; h1B[u] = ov * fast_tanh(c); }
        }
    }

    // ---- classifier: waves 0,1 produce 5 outputs each, both samples ----
    if (wid < 2) {
        #pragma unroll
        for (int k = 0; k < 5; ++k) {
            const int o = wid * 5 + k;
            const float* wc = w_cls + o * HDIM;
            float aA = b_cls[o], aB = b_cls[o];
            #pragma unroll
            for (int j = 0; j < HDIM; ++j) {
                aA += h1A[j] * wc[j];
                aB += h1B[j] * wc[j];
            }
            out[(size_t)sA * 10 + o] = aA;
            out[(size_t)sB * 10 + o] = aB;
        }
    }
}

extern "C" void kernel_launch(void* const* d_in, const int* in_sizes, int n_in,
                              void* d_out, int out_size, void* d_ws, size_t ws_size,
                              hipStream_t stream) {
    const float* x     = (const float*)d_in[0];
    const float* w_ih0 = (const float*)d_in[1];
    const float* w_hh0 = (const float*)d_in[2];
    const float* b_ih0 = (const float*)d_in[3];
    const float* b_hh0 = (const float*)d_in[4];
    const float* w_ih1 = (const float*)d_in[5];
    const float* w_hh1 = (const float*)d_in[6];
    const float* b_ih1 = (const float*)d_in[7];
    const float* b_hh1 = (const float*)d_in[8];
    const float* w_cls = (const float*)d_in[9];
    const float* b_cls = (const float*)d_in[10];
    float* out = (float*)d_out;

    const int B = in_sizes[0] / (TSTEPS * DDIM);   // 32768
    const int grid = B / SPB;                      // 256 blocks, 8 waves each

    hipLaunchKernelGGL(lstm2_cls_kernel, dim3(grid), dim3(512), 0, stream,
                       x, w_ih0, w_hh0, b_ih0, b_hh0,
                       w_ih1, w_hh1, b_ih1, b_hh1,
                       w_cls, b_cls, out);
}